// Round 1
// baseline (729.404 us; speedup 1.0000x reference)
//
#include <hip/hip_runtime.h>
#include <stdint.h>

#define FP8_MAX 448.0f

typedef float floatx4 __attribute__((ext_vector_type(4)));

// ---- async global->LDS 16B copy (global_load_lds_dwordx4) ----
// NOTE: HW writes LDS at wave-uniform base + lane*16; our chunk layout is
// constructed so chunk == wave_base + lane, i.e. contiguous per wave.
__device__ __forceinline__ void async_copy16(const void* g, void* s) {
    __builtin_amdgcn_global_load_lds(
        (const __attribute__((address_space(1))) void*)g,
        (__attribute__((address_space(3))) void*)s,
        16, 0, 0);
}

// ---- fp8 e4m3 quantization: dst[i] = fp8(clamp(src[i]/scale, +-448)) ----
// 16 elements per thread: 4x float4 load -> 16 fp8 bytes -> one int4 store.
__global__ void __launch_bounds__(256) quant_fp8_kernel(
    const float* __restrict__ src, const float* __restrict__ scale,
    uint8_t* __restrict__ dst, long n16)
{
    long g = (long)blockIdx.x * 256 + threadIdx.x;
    if (g >= n16) return;
    long i = g * 16;
    float s = 1.0f;
    if (scale) s = scale[0];
    const float4* p = (const float4*)(src + i);
    int out[4];
#pragma unroll
    for (int j = 0; j < 4; ++j) {
        float4 v = p[j];
        float a, b, c, d;
        if (scale) { a = v.x / s; b = v.y / s; c = v.z / s; d = v.w / s; }
        else       { a = v.x;     b = v.y;     c = v.z;     d = v.w;     }
        a = fminf(fmaxf(a, -FP8_MAX), FP8_MAX);
        b = fminf(fmaxf(b, -FP8_MAX), FP8_MAX);
        c = fminf(fmaxf(c, -FP8_MAX), FP8_MAX);
        d = fminf(fmaxf(d, -FP8_MAX), FP8_MAX);
        int pk = 0;
        pk = __builtin_amdgcn_cvt_pk_fp8_f32(a, b, pk, false);  // bytes 0..1
        pk = __builtin_amdgcn_cvt_pk_fp8_f32(c, d, pk, true);   // bytes 2..3
        out[j] = pk;
    }
    *(int4*)(dst + i) = make_int4(out[0], out[1], out[2], out[3]);
}

// ---- fp8 GEMM, m97/m145 structure ----
// A: qx [M][K] fp8 row-major, B: qw [N][K] fp8 row-major (B^T form, K-contig)
// C[m][n] = sum_k A[m][k]*B[n][k];  out = C*osc + bias[n]
// Block tile 128x128, BK=64; 256 threads = 4 waves in 2x2, each wave 64x64
// via 4x4 grid of mfma_f32_16x16x32_fp8_fp8.
__global__ void __launch_bounds__(256, 2) gemm_fp8_kernel(
    const uint8_t* __restrict__ A, const uint8_t* __restrict__ B,
    const float* __restrict__ bias,
    const float* __restrict__ in_scale, const float* __restrict__ w_scale,
    float* __restrict__ C, int M, int N, int K)
{
    __shared__ __align__(16) uint8_t As[128 * 64];
    __shared__ __align__(16) uint8_t Bs[128 * 64];

    const int tid  = threadIdx.x;
    const int lane = tid & 63;
    const int wid  = tid >> 6;
    const int wm   = wid >> 1;       // wave row (0..1)
    const int wn   = wid & 1;        // wave col (0..1)
    const int m0   = blockIdx.y * 128;
    const int n0   = blockIdx.x * 128;

    const int mlane = lane & 15;     // MFMA row/col within 16
    const int quad  = lane >> 4;     // 0..3

    // staging: 512 chunks of 16B per matrix; chunk c -> row c>>2, col (c&3)*16
    const int c0 = tid, c1 = tid + 256;
    const int rA0 = c0 >> 2, cA0 = (c0 & 3) * 16;
    const int rA1 = c1 >> 2, cA1 = (c1 & 3) * 16;

    const uint8_t* Ab = A + (size_t)m0 * K;
    const uint8_t* Bb = B + (size_t)n0 * K;

    floatx4 acc[4][4];
#pragma unroll
    for (int i = 0; i < 4; ++i)
#pragma unroll
        for (int j = 0; j < 4; ++j) acc[i][j] = (floatx4){0.f, 0.f, 0.f, 0.f};

    // LDS read byte offsets: frag(row, kk) at row*64 + kk*32 + quad*8
    const int aoff = (wm * 64 + mlane) * 64 + quad * 8;
    const int boff = (wn * 64 + mlane) * 64 + quad * 8;

    for (int kt = 0; kt < K; kt += 64) {
        async_copy16(Ab + (size_t)rA0 * K + kt + cA0, As + c0 * 16);
        async_copy16(Ab + (size_t)rA1 * K + kt + cA1, As + c1 * 16);
        async_copy16(Bb + (size_t)rA0 * K + kt + cA0, Bs + c0 * 16);
        async_copy16(Bb + (size_t)rA1 * K + kt + cA1, Bs + c1 * 16);
        __syncthreads();   // compiler emits vmcnt(0) drain before barrier

#pragma unroll
        for (int kk = 0; kk < 2; ++kk) {
            long av[4], bv[4];
#pragma unroll
            for (int mi = 0; mi < 4; ++mi)
                av[mi] = *(const long*)(As + aoff + mi * 16 * 64 + kk * 32);
#pragma unroll
            for (int ni = 0; ni < 4; ++ni)
                bv[ni] = *(const long*)(Bs + boff + ni * 16 * 64 + kk * 32);
#pragma unroll
            for (int mi = 0; mi < 4; ++mi)
#pragma unroll
                for (int ni = 0; ni < 4; ++ni)
                    acc[mi][ni] = __builtin_amdgcn_mfma_f32_16x16x32_fp8_fp8(
                        av[mi], bv[ni], acc[mi][ni], 0, 0, 0);
        }
        __syncthreads();   // protect LDS overwrite next iteration
    }

    const float osc = in_scale[0] * w_scale[0];

    // epilogue: C/D layout col = lane&15, row = quad*4 + reg
#pragma unroll
    for (int mi = 0; mi < 4; ++mi) {
#pragma unroll
        for (int ni = 0; ni < 4; ++ni) {
            const int gn = n0 + wn * 64 + ni * 16 + mlane;
            const float bvv = bias[gn];
#pragma unroll
            for (int r = 0; r < 4; ++r) {
                const int gm = m0 + wm * 64 + mi * 16 + quad * 4 + r;
                C[(size_t)gm * N + gn] = acc[mi][ni][r] * osc + bvv;
            }
        }
    }
}

extern "C" void kernel_launch(void* const* d_in, const int* in_sizes, int n_in,
                              void* d_out, int out_size, void* d_ws, size_t ws_size,
                              hipStream_t stream) {
    const float* x        = (const float*)d_in[0];  // [M][K]
    const float* weight   = (const float*)d_in[1];  // [N][K], fp8-grid values
    const float* w_scale  = (const float*)d_in[2];  // [1]
    const float* bias     = (const float*)d_in[3];  // [N]
    const float* in_scale = (const float*)d_in[4];  // [1]
    float* out = (float*)d_out;

    const int N = in_sizes[3];                 // D_OUT = 4096
    const int K = in_sizes[1] / N;             // D_IN  = 4096
    const int M = in_sizes[0] / K;             // N_TOK = 8192

    uint8_t* qx = (uint8_t*)d_ws;                          // M*K fp8 (32 MB)
    uint8_t* qw = (uint8_t*)d_ws + (size_t)M * K;          // N*K fp8 (16 MB)

    const long nx16 = (long)M * K / 16;
    const long nw16 = (long)N * K / 16;
    quant_fp8_kernel<<<(nx16 + 255) / 256, 256, 0, stream>>>(x, in_scale, qx, nx16);
    quant_fp8_kernel<<<(nw16 + 255) / 256, 256, 0, stream>>>(weight, nullptr, qw, nw16);

    dim3 grid(N / 128, M / 128);  // (32, 64)
    gemm_fp8_kernel<<<grid, 256, 0, stream>>>(qx, qw, bias, in_scale, w_scale,
                                              out, M, N, K);
}

// Round 2
// 434.760 us; speedup vs baseline: 1.6777x; 1.6777x over previous
//
#include <hip/hip_runtime.h>
#include <stdint.h>

#define FP8_MAX 448.0f

typedef float floatx4 __attribute__((ext_vector_type(4)));
typedef long  longx2  __attribute__((ext_vector_type(2)));

// ---- async global->LDS 16B copy (global_load_lds_dwordx4) ----
// HW writes LDS at wave-uniform base + lane*16; chunk layout is constructed
// so chunk == wave_base + lane (contiguous per wave).
__device__ __forceinline__ void async_copy16(const void* g, void* s) {
    __builtin_amdgcn_global_load_lds(
        (const __attribute__((address_space(1))) void*)g,
        (__attribute__((address_space(3))) void*)s,
        16, 0, 0);
}

// ---- fp8 e4m3 quantization: dst[i] = fp8(clamp(src[i]*inv_scale, +-448)) ----
// 16 elements per thread: 4x float4 load -> 16 fp8 bytes -> one int4 store.
__global__ void __launch_bounds__(256) quant_fp8_kernel(
    const float* __restrict__ src, const float* __restrict__ scale,
    uint8_t* __restrict__ dst, long n16)
{
    long g = (long)blockIdx.x * 256 + threadIdx.x;
    if (g >= n16) return;
    long i = g * 16;
    float inv = 1.0f;
    if (scale) inv = 1.0f / scale[0];   // one div/thread; tolerance >> fp8 tie-flip
    const float4* p = (const float4*)(src + i);
    int out[4];
#pragma unroll
    for (int j = 0; j < 4; ++j) {
        float4 v = p[j];
        float a = v.x * inv, b = v.y * inv, c = v.z * inv, d = v.w * inv;
        a = fminf(fmaxf(a, -FP8_MAX), FP8_MAX);
        b = fminf(fmaxf(b, -FP8_MAX), FP8_MAX);
        c = fminf(fmaxf(c, -FP8_MAX), FP8_MAX);
        d = fminf(fmaxf(d, -FP8_MAX), FP8_MAX);
        int pk = 0;
        pk = __builtin_amdgcn_cvt_pk_fp8_f32(a, b, pk, false);  // bytes 0..1
        pk = __builtin_amdgcn_cvt_pk_fp8_f32(c, d, pk, true);   // bytes 2..3
        out[j] = pk;
    }
    *(int4*)(dst + i) = make_int4(out[0], out[1], out[2], out[3]);
}

// ---- fp8 GEMM, m97/m145 structure, conflict-free b128 LDS reads ----
// A: qx [M][K] fp8 row-major, B: qw [N][K] fp8 row-major (B^T, K-contig)
// C[m][n] = sum_k A[m][k]*B[n][k];  out = C*osc + bias[n]
// Block tile 128x128, BK=64; 256 threads = 4 waves (2x2), each wave 64x64
// via 4x4 grid of mfma_f32_16x16x32_fp8_fp8.
//
// LDS fragment read: one ds_read_b128 per (wave,mi): addr = base +
// (lane&15)*64 + (lane>>4)*16 -> linear 1024B sweep, 0 bank conflicts.
// The 16B hold k-positions quad*16..+16 — a k-permutation of the MFMA
// native order. Valid: A and B use the same permutation (lo 8B -> MFMA#0,
// hi 8B -> MFMA#1), and dot products are k-permutation-invariant.
__global__ void __launch_bounds__(256, 2) gemm_fp8_kernel(
    const uint8_t* __restrict__ A, const uint8_t* __restrict__ B,
    const float* __restrict__ bias,
    const float* __restrict__ in_scale, const float* __restrict__ w_scale,
    float* __restrict__ C, int M, int N, int K)
{
    __shared__ __align__(16) uint8_t As[128 * 64];
    __shared__ __align__(16) uint8_t Bs[128 * 64];

    const int tid  = threadIdx.x;
    const int lane = tid & 63;
    const int wid  = tid >> 6;
    const int wm   = wid >> 1;       // wave row (0..1)
    const int wn   = wid & 1;        // wave col (0..1)
    const int m0   = blockIdx.y * 128;
    const int n0   = blockIdx.x * 128;

    const int mlane = lane & 15;     // MFMA row/col within 16
    const int quad  = lane >> 4;     // 0..3

    // staging: 512 chunks of 16B per matrix; chunk c -> row c>>2, col (c&3)*16
    const int c0 = tid, c1 = tid + 256;
    const int rA0 = c0 >> 2, cA0 = (c0 & 3) * 16;
    const int rA1 = c1 >> 2, cA1 = (c1 & 3) * 16;

    const uint8_t* Ab = A + (size_t)m0 * K;
    const uint8_t* Bb = B + (size_t)n0 * K;

    floatx4 acc[4][4];
#pragma unroll
    for (int i = 0; i < 4; ++i)
#pragma unroll
        for (int j = 0; j < 4; ++j) acc[i][j] = (floatx4){0.f, 0.f, 0.f, 0.f};

    // conflict-free b128 read offsets (bytes)
    const int aoff = (wm * 64 + mlane) * 64 + quad * 16;
    const int boff = (wn * 64 + mlane) * 64 + quad * 16;

    for (int kt = 0; kt < K; kt += 64) {
        async_copy16(Ab + (size_t)rA0 * K + kt + cA0, As + c0 * 16);
        async_copy16(Ab + (size_t)rA1 * K + kt + cA1, As + c1 * 16);
        async_copy16(Bb + (size_t)rA0 * K + kt + cA0, Bs + c0 * 16);
        async_copy16(Bb + (size_t)rA1 * K + kt + cA1, Bs + c1 * 16);
        __syncthreads();   // compiler emits vmcnt(0) drain before barrier

        longx2 av[4], bv[4];
#pragma unroll
        for (int mi = 0; mi < 4; ++mi)
            av[mi] = *(const longx2*)(As + aoff + mi * 16 * 64);
#pragma unroll
        for (int ni = 0; ni < 4; ++ni)
            bv[ni] = *(const longx2*)(Bs + boff + ni * 16 * 64);

#pragma unroll
        for (int mi = 0; mi < 4; ++mi)
#pragma unroll
            for (int ni = 0; ni < 4; ++ni)
                acc[mi][ni] = __builtin_amdgcn_mfma_f32_16x16x32_fp8_fp8(
                    av[mi].x, bv[ni].x, acc[mi][ni], 0, 0, 0);
#pragma unroll
        for (int mi = 0; mi < 4; ++mi)
#pragma unroll
            for (int ni = 0; ni < 4; ++ni)
                acc[mi][ni] = __builtin_amdgcn_mfma_f32_16x16x32_fp8_fp8(
                    av[mi].y, bv[ni].y, acc[mi][ni], 0, 0, 0);

        __syncthreads();   // protect LDS overwrite next iteration
    }

    const float osc = in_scale[0] * w_scale[0];

    // epilogue: C/D layout col = lane&15, row = quad*4 + reg
#pragma unroll
    for (int mi = 0; mi < 4; ++mi) {
#pragma unroll
        for (int ni = 0; ni < 4; ++ni) {
            const int gn = n0 + wn * 64 + ni * 16 + mlane;
            const float bvv = bias[gn];
#pragma unroll
            for (int r = 0; r < 4; ++r) {
                const int gm = m0 + wm * 64 + mi * 16 + quad * 4 + r;
                C[(size_t)gm * N + gn] = acc[mi][ni][r] * osc + bvv;
            }
        }
    }
}

extern "C" void kernel_launch(void* const* d_in, const int* in_sizes, int n_in,
                              void* d_out, int out_size, void* d_ws, size_t ws_size,
                              hipStream_t stream) {
    const float* x        = (const float*)d_in[0];  // [M][K]
    const float* weight   = (const float*)d_in[1];  // [N][K], fp8-grid values
    const float* w_scale  = (const float*)d_in[2];  // [1]
    const float* bias     = (const float*)d_in[3];  // [N]
    const float* in_scale = (const float*)d_in[4];  // [1]
    float* out = (float*)d_out;

    const int N = in_sizes[3];                 // D_OUT = 4096
    const int K = in_sizes[1] / N;             // D_IN  = 4096
    const int M = in_sizes[0] / K;             // N_TOK = 8192

    uint8_t* qx = (uint8_t*)d_ws;                          // M*K fp8 (32 MB)
    uint8_t* qw = (uint8_t*)d_ws + (size_t)M * K;          // N*K fp8 (16 MB)

    const long nx16 = (long)M * K / 16;
    const long nw16 = (long)N * K / 16;
    quant_fp8_kernel<<<(nx16 + 255) / 256, 256, 0, stream>>>(x, in_scale, qx, nx16);
    quant_fp8_kernel<<<(nw16 + 255) / 256, 256, 0, stream>>>(weight, nullptr, qw, nw16);

    dim3 grid(N / 128, M / 128);  // (32, 64)
    gemm_fp8_kernel<<<grid, 256, 0, stream>>>(qx, qw, bias, in_scale, w_scale,
                                              out, M, N, K);
}